// Round 12
// baseline (553.460 us; speedup 1.0000x reference)
//
#include <hip/hip_runtime.h>
#include <hip/hip_bf16.h>

#define T_DIM 8192
#define H_DIM 2048
#define F_DIM 5632

typedef __attribute__((ext_vector_type(4))) float f32x4;
typedef __attribute__((ext_vector_type(8))) short bf16x8;

static __device__ __forceinline__ void gload16(const void* g, void* l) {
    __builtin_amdgcn_global_load_lds(
        (const __attribute__((address_space(1))) void*)g,
        (__attribute__((address_space(3))) void*)l,
        16, 0, 0);
}

static __device__ __forceinline__ unsigned short f2bf(float f) {
    unsigned int u = __float_as_uint(f);
    u += 0x7fffu + ((u >> 16) & 1u);
    return (unsigned short)(u >> 16);
}

// ---- f32 -> bf16 conversion: X ----
__global__ __launch_bounds__(256)
void cvt_x(const float* __restrict__ src, unsigned short* __restrict__ dst, long n)
{
    const long stride = (long)gridDim.x * blockDim.x;
    for (long i = (long)blockIdx.x * blockDim.x + threadIdx.x; i * 4 < n; i += stride) {
        const float4 v = *(const float4*)(src + i * 4);
        ushort4 o;
        o.x = f2bf(v.x); o.y = f2bf(v.y); o.z = f2bf(v.z); o.w = f2bf(v.w);
        *(ushort4*)(dst + i * 4) = o;
    }
}

// ---- f32 -> bf16 weight conversion.
// W1/W2 interleaved into W12[11264 x 2048] at 16-row granularity:
//   W1 row r -> R = (r>>4)*32 + (r&15);  W2 row r -> R + 16
// W3 converted linearly. (r10-verified mapping.)
__global__ __launch_bounds__(256)
void cvt_w(const float* __restrict__ w1, const float* __restrict__ w2,
           const float* __restrict__ w3, const int* __restrict__ eidx,
           unsigned short* __restrict__ W12, unsigned short* __restrict__ W3b)
{
    const long seg = (long)F_DIM * H_DIM;
    const long e   = (long)(*eidx);
    const long nchunks = 3 * seg / 4;
    const long stride = (long)gridDim.x * blockDim.x;
    for (long i = (long)blockIdx.x * blockDim.x + threadIdx.x; i < nchunks; i += stride) {
        const long t = i * 4;
        const int  s = (int)(t / seg);
        const long o = t - (long)s * seg;
        const float4 v = *(const float4*)((s == 0 ? w1 : s == 1 ? w2 : w3) + e * seg + o);
        ushort4 ov;
        ov.x = f2bf(v.x); ov.y = f2bf(v.y); ov.z = f2bf(v.z); ov.w = f2bf(v.w);
        if (s == 2) {
            *(ushort4*)(W3b + o) = ov;
        } else {
            const long r   = o >> 11;
            const long col = o & 2047;
            const long R   = (r >> 4) * 32 + (r & 15) + (s == 1 ? 16 : 0);
            *(ushort4*)(W12 + R * 2048 + col) = ov;
        }
    }
}

// ---- staging / frag helpers (XOR-swizzled, rule #21) ----
static __device__ __forceinline__ void stage_half(const unsigned short* __restrict__ g,
                                                  long grow0, long ldk, long kb,
                                                  unsigned short* l, int t, int i0)
{
    const int r  = t >> 3;
    const int cc = ((t & 7) ^ (r & 7)) << 3;   // inverse-swizzled source column
    #pragma unroll
    for (int ii = i0; ii < i0 + 2; ++ii)
        gload16(g + (grow0 + ii * 64 + r) * ldk + kb + cc,
                l + ii * 4096 + t * 8);
}

static __device__ __forceinline__ bf16x8 ldsfrag(const unsigned short* base,
                                                 int row, int kk, int q)
{
    return *(const bf16x8*)(base + row * 64 + (((kk * 4 + q) ^ (row & 7)) << 3));
}

// ---- FC1: tile 128 M-rows x 128 out-cols (B-tile 256 interleaved W12 rows).
// 8 waves = 2M x 4N; per wave Mf=4 x Nf=4 frags -> 16 ds_read per 32 MFMA
// (was 20 at r10's 8x2). LDS 64 KB (A dbuf 2x16 + B single 32) -> 2 blocks/CU.
// acc[mi][0/2]=gate, acc[mi][1/3]=up for col-blocks 0/1.
__global__ __launch_bounds__(512, 4)
void gemm_fc1(const unsigned short* __restrict__ X,
              const unsigned short* __restrict__ W12,
              unsigned short* __restrict__ Hout)
{
    constexpr int NK = H_DIM / 64;   // 32

    __shared__ __align__(16) unsigned short sAll[32768];  // 64 KiB

    const int tid  = threadIdx.x;
    const int lane = tid & 63;
    const int wid  = tid >> 6;
    const int wm   = wid >> 2;       // 0..1 : 64-row M halves
    const int wn   = wid & 3;        // 0..3 : 32-col N groups
    const int q    = lane >> 4;
    const int lr   = lane & 15;

    // grid 2816 = 8 XCD x 352; per XCD: bn-major, 8 bm per XCD
    const int bid = blockIdx.x;
    const int x   = bid & 7;
    const int ii  = bid >> 3;        // 0..351
    const int bn  = ii >> 3;         // 0..43
    const int bm  = x * 8 + (ii & 7);// 0..63

    const long arow0 = (long)bm * 128;
    const long brow0 = (long)bn * 256;   // W12 rows

    unsigned short* sB = sAll + 16384;   // 32 KB single-buffered B

    f32x4 acc[4][4] = {};

    // prologue: A(0) -> bufA0 (2 issues); B(0) -> sB (4 issues)
    stage_half(X,   arow0, H_DIM, 0, sAll, tid, 0);
    stage_half(W12, brow0, H_DIM, 0, sB,   tid, 0);
    stage_half(W12, brow0, H_DIM, 0, sB,   tid, 2);

    for (int j = 0; j < NK; ++j) {
        unsigned short* la = sAll + (j & 1) * 8192;

        if (j + 1 < NK) {
            unsigned short* na = sAll + ((j + 1) & 1) * 8192;
            stage_half(X, arow0, H_DIM, (long)(j + 1) * 64, na, tid, 0);
            // queue: [A(j):2, B(j):4, A(j+1):2] -> keep 2 newest
            asm volatile("s_waitcnt vmcnt(2)" ::: "memory");
        } else {
            asm volatile("s_waitcnt vmcnt(0)" ::: "memory");
        }
        __builtin_amdgcn_s_barrier();        // TOP: A(j),B(j) visible

        // hoist B frags: wave-local 64 B-rows = {gate,up} x 2 col-blocks
        bf16x8 bf[4][2];
        #pragma unroll
        for (int nf = 0; nf < 4; ++nf)
            #pragma unroll
            for (int kk = 0; kk < 2; ++kk)
                bf[nf][kk] = ldsfrag(sB, wn * 64 + nf * 16 + lr, kk, q);

        // ---- phase 0: mi 0,1 ----
        {
            bf16x8 af[2][2];
            #pragma unroll
            for (int mi = 0; mi < 2; ++mi)
                #pragma unroll
                for (int kk = 0; kk < 2; ++kk)
                    af[mi][kk] = ldsfrag(la, wm * 64 + mi * 16 + lr, kk, q);
            __builtin_amdgcn_s_barrier();
            __builtin_amdgcn_s_setprio(1);
            #pragma unroll
            for (int mi = 0; mi < 2; ++mi)
                #pragma unroll
                for (int nf = 0; nf < 4; ++nf)
                    #pragma unroll
                    for (int kk = 0; kk < 2; ++kk)
                        acc[mi][nf] = __builtin_amdgcn_mfma_f32_16x16x32_bf16(
                            af[mi][kk], bf[nf][kk], acc[mi][nf], 0, 0, 0);
            __builtin_amdgcn_s_setprio(0);
            __builtin_amdgcn_s_barrier();
        }

        // ---- phase 1: mi 2,3 (+ stage B(j+1) into sB, 4 issues) ----
        {
            bf16x8 af[2][2];
            #pragma unroll
            for (int mi = 0; mi < 2; ++mi)
                #pragma unroll
                for (int kk = 0; kk < 2; ++kk)
                    af[mi][kk] = ldsfrag(la, wm * 64 + (mi + 2) * 16 + lr, kk, q);
            if (j + 1 < NK) {
                stage_half(W12, brow0, H_DIM, (long)(j + 1) * 64, sB, tid, 0);
                stage_half(W12, brow0, H_DIM, (long)(j + 1) * 64, sB, tid, 2);
            }
            __builtin_amdgcn_s_barrier();
            __builtin_amdgcn_s_setprio(1);
            #pragma unroll
            for (int mi = 0; mi < 2; ++mi)
                #pragma unroll
                for (int nf = 0; nf < 4; ++nf)
                    #pragma unroll
                    for (int kk = 0; kk < 2; ++kk)
                        acc[mi + 2][nf] = __builtin_amdgcn_mfma_f32_16x16x32_bf16(
                            af[mi][kk], bf[nf][kk], acc[mi + 2][nf], 0, 0, 0);
            __builtin_amdgcn_s_setprio(0);
            __builtin_amdgcn_s_barrier();
        }
    }

    // terminal epilogue: pairs (gate,up) = (acc[*][2nj], acc[*][2nj+1])
    const long orow = (long)bm * 128 + wm * 64;
    const long ocolb = (long)bn * 128 + wn * 32;
    #pragma unroll
    for (int mi = 0; mi < 4; ++mi)
        #pragma unroll
        for (int nj = 0; nj < 2; ++nj)
            #pragma unroll
            for (int r = 0; r < 4; ++r) {
                const float g = acc[mi][2 * nj][r];
                const float u = acc[mi][2 * nj + 1][r];
                const float h = __fdividef(g, 1.0f + __expf(-g)) * u;
                Hout[(orow + mi * 16 + q * 4 + r) * (long)F_DIM +
                     (ocolb + nj * 16 + lr)] = f2bf(h);
            }
}

// ---- GEMM2 phase (unchanged proven template) ----
#define PHASE_BODY(p, STAGE_STMT)                                              \
    {                                                                          \
        bf16x8 af[2][2];                                                       \
        _Pragma("unroll")                                                      \
        for (int l_ = 0; l_ < 2; ++l_)                                         \
            _Pragma("unroll")                                                  \
            for (int kk = 0; kk < 2; ++kk)                                     \
                af[l_][kk] = ldsfrag(la, wm * 128 + (p) * 32 + l_ * 16 + lr, kk, q); \
        STAGE_STMT;                                                            \
        __builtin_amdgcn_s_barrier();                                          \
        __builtin_amdgcn_s_setprio(1);                                         \
        _Pragma("unroll")                                                      \
        for (int l_ = 0; l_ < 2; ++l_)                                         \
            _Pragma("unroll")                                                  \
            for (int ni = 0; ni < 4; ++ni)                                     \
                _Pragma("unroll")                                              \
                for (int kk = 0; kk < 2; ++kk)                                 \
                    acc[(p) * 2 + l_][ni] = __builtin_amdgcn_mfma_f32_16x16x32_bf16( \
                        af[l_][kk], bf[ni][kk], acc[(p) * 2 + l_][ni], 0, 0, 0);     \
        __builtin_amdgcn_s_setprio(0);                                         \
        __builtin_amdgcn_s_barrier();                                          \
    }

// ---- GEMM2: Out = H * W3^T.  H [T,F] bf16, W3 [H,F] bf16, Out [T,H] f32 ----
__global__ __launch_bounds__(512, 2)
void gemm_out(const unsigned short* __restrict__ A,
              const unsigned short* __restrict__ B,
              float* __restrict__ Out)
{
    constexpr int NK  = F_DIM / 64;   // 88
    constexpr int NBN = H_DIM / 256;  // 8

    __shared__ __align__(16) unsigned short sAll[4 * 16384];

    const int tid  = threadIdx.x;
    const int lane = tid & 63;
    const int wid  = tid >> 6;
    const int wm   = wid >> 2;
    const int wn   = wid & 3;
    const int q    = lane >> 4;
    const int lr   = lane & 15;

    const int nwg = gridDim.x;                 // 256
    const int bid = blockIdx.x;
    const int cpx = nwg >> 3;
    const int swz = (bid & 7) * cpx + (bid >> 3);
    const int bm  = swz / NBN;
    const int bn  = swz % NBN;

    const long arow0 = (long)bm * 256;
    const long brow0 = (long)bn * 256;

    f32x4 acc[8][4] = {};

    stage_half(A, arow0, F_DIM, 0,  sAll,          tid, 0);
    stage_half(A, arow0, F_DIM, 0,  sAll,          tid, 2);
    stage_half(B, brow0, F_DIM, 0,  sAll + 16384,  tid, 0);
    stage_half(B, brow0, F_DIM, 0,  sAll + 16384,  tid, 2);
    stage_half(B, brow0, F_DIM, 64, sAll + 49152,  tid, 0);
    stage_half(B, brow0, F_DIM, 64, sAll + 49152,  tid, 2);

    for (int j = 0; j < NK; ++j) {
        unsigned short* la = sAll + (j & 1) * 32768;
        unsigned short* lb = la + 16384;

        if (j + 1 < NK) {
            unsigned short* na = sAll + ((j + 1) & 1) * 32768;
            stage_half(A, arow0, F_DIM, (long)(j + 1) * 64, na, tid, 0);
            stage_half(A, arow0, F_DIM, (long)(j + 1) * 64, na, tid, 2);
            asm volatile("s_waitcnt vmcnt(8)" ::: "memory");
        } else {
            asm volatile("s_waitcnt vmcnt(0)" ::: "memory");
        }
        __builtin_amdgcn_s_barrier();

        bf16x8 bf[4][2];
        #pragma unroll
        for (int ni = 0; ni < 4; ++ni)
            #pragma unroll
            for (int kk = 0; kk < 2; ++kk)
                bf[ni][kk] = ldsfrag(lb, wn * 64 + ni * 16 + lr, kk, q);

        PHASE_BODY(0, {})
        PHASE_BODY(1, { if (j + 2 < NK) stage_half(B, brow0, F_DIM, (long)(j + 2) * 64, lb, tid, 0); })
        PHASE_BODY(2, { if (j + 2 < NK) stage_half(B, brow0, F_DIM, (long)(j + 2) * 64, lb, tid, 2); })
        PHASE_BODY(3, {})
    }

    const long orow = (long)bm * 256 + wm * 128;
    const long ocol = (long)bn * 256 + wn * 64;
    #pragma unroll
    for (int mi = 0; mi < 8; ++mi)
        #pragma unroll
        for (int ni = 0; ni < 4; ++ni)
            #pragma unroll
            for (int r = 0; r < 4; ++r)
                Out[(orow + mi * 16 + q * 4 + r) * (long)H_DIM + (ocol + ni * 16 + lr)]
                    = acc[mi][ni][r];
}

extern "C" void kernel_launch(void* const* d_in, const int* in_sizes, int n_in,
                              void* d_out, int out_size, void* d_ws, size_t ws_size,
                              hipStream_t stream)
{
    const int*   eidx = (const int*)d_in[0];
    const float* x    = (const float*)d_in[1];
    const float* w1   = (const float*)d_in[2];
    const float* w2   = (const float*)d_in[3];
    const float* w3   = (const float*)d_in[4];
    float* out = (float*)d_out;

    const size_t SZ_X = (size_t)T_DIM * H_DIM;
    const size_t SZ_W = (size_t)F_DIM * H_DIM;

    unsigned short* Xb  = (unsigned short*)d_ws;
    unsigned short* W12 = Xb  + SZ_X;            // [11264 x 2048] interleaved
    unsigned short* W3b = W12 + 2 * SZ_W;
    unsigned short* Hb  = W3b + SZ_W;

    cvt_x<<<2048, 256, 0, stream>>>(x, Xb, (long)SZ_X);
    cvt_w<<<2048, 256, 0, stream>>>(w1, w2, w3, eidx, W12, W3b);

    gemm_fc1<<<2816, 512, 0, stream>>>(Xb, W12, Hb);
    gemm_out<<<(T_DIM / 256) * (H_DIM / 256), 512, 0, stream>>>(Hb, W3b, out);
}